// Round 10
// baseline (38.713 us; speedup 1.0000x reference)
//
#include <hip/hip_runtime.h>

// out[b, n*7+c, w] = sum_k x[b, w*3+k-21, c] * kern[n, k]   (n in 0..72)
// out[b, 511,   w] = sum_k x[b, w*3+k-21, 0] * kern[73, k]
// Output (32, 512, 2736) fp32.
//
// R10: gp merged (stage once, all 74 rows per block), 512-thread blocks.
//   grid (8 wq, 32 b) = 256 blocks = exactly 1/CU, 8 waves stripe n.
//   tiles {88,88,88,84,84,84,84,84} chunks — bases mult of 4 chunks = 64B
//   aligned. Wave store run per (n,c): 88 chunks = 1408 B contiguous.

typedef float f32x4 __attribute__((ext_vector_type(4)));

constexpr int Bn   = 32;
constexpr int Sn   = 8192;
constexpr int Cn   = 7;
constexpr int Kn   = 8;
constexpr int PADn = 21;
constexpr int Wn   = 2736;          // (8192+21-8)/3 + 1
constexpr int OCH  = 512;           // 73*7 + 1
constexpr int MAXCH = 88;           // max chunks per tile
constexpr int MAXSAMP = MAXCH * 12 + 5;       // 1061
constexpr int CSTR = 1064;          // per-channel LDS stride (mult of 4)

__global__ __launch_bounds__(512)
void conv_v10(const float* __restrict__ x, const float* __restrict__ kern,
              float* __restrict__ out) {
    __shared__ float lx[Cn * CSTR];      // 29.8 KB

    const int tid = threadIdx.x;
    const int wq  = blockIdx.x;          // 0..7   (w-tile)
    const int b   = blockIdx.y;          // 0..31

    // tile geometry: wq<3 -> 88 chunks, else 84
    const int cht  = (wq < 3) ? 88 : 84;
    const int coff = (wq < 3) ? 88 * wq : 264 + 84 * (wq - 3);
    const int samp = cht * 12 + 5;

    // ---- stage: dense coalesced global reads -> per-channel LDS rows ----
    const int g0 = (12 * coff - PADn) * Cn;   // first float of tile region
    const float* xb = x + (size_t)b * Sn * Cn;
    for (int i = tid; i < samp * Cn; i += 512) {
        int gg = g0 + i;
        float v = (gg >= 0 && gg < Sn * Cn) ? xb[gg] : 0.0f;
        int s = i / 7;
        int c = i - 7 * s;
        lx[c * CSTR + s] = v;
    }
    __syncthreads();

    const int lane = tid & 63;
    const int r    = __builtin_amdgcn_readfirstlane(tid >> 6);   // wave 0..7
    const int ch0  = lane;               // always < cht (84/88 > 63)
    const int ch1  = lane + 64;
    const bool p1  = (ch1 < cht);        // lanes 0..19 / 0..23

    float* ob = out + (size_t)b * OCH * Wn + 4 * coff;

    for (int c = 0; c < Cn; ++c) {
        const float* lc = lx + c * CSTR;
        float xw0[17], xw1[17];
        {
            const float* lr = lc + 12 * ch0;
            *reinterpret_cast<f32x4*>(xw0 + 0)  = *reinterpret_cast<const f32x4*>(lr + 0);
            *reinterpret_cast<f32x4*>(xw0 + 4)  = *reinterpret_cast<const f32x4*>(lr + 4);
            *reinterpret_cast<f32x4*>(xw0 + 8)  = *reinterpret_cast<const f32x4*>(lr + 8);
            *reinterpret_cast<f32x4*>(xw0 + 12) = *reinterpret_cast<const f32x4*>(lr + 12);
            xw0[16] = lr[16];
        }
        if (p1) {
            const float* lr = lc + 12 * ch1;
            *reinterpret_cast<f32x4*>(xw1 + 0)  = *reinterpret_cast<const f32x4*>(lr + 0);
            *reinterpret_cast<f32x4*>(xw1 + 4)  = *reinterpret_cast<const f32x4*>(lr + 4);
            *reinterpret_cast<f32x4*>(xw1 + 8)  = *reinterpret_cast<const f32x4*>(lr + 8);
            *reinterpret_cast<f32x4*>(xw1 + 12) = *reinterpret_cast<const f32x4*>(lr + 12);
            xw1[16] = lr[16];
        }

        for (int n = r; n < 73; n += 8) {        // wave-uniform rows
            const float* kr = kern + n * Kn;
            float kv[8];
#pragma unroll
            for (int k = 0; k < 8; ++k) kv[k] = kr[k];
            float* orow = ob + (size_t)(n * 7 + c) * Wn;
            {
                float a0 = 0.f, a1 = 0.f, a2 = 0.f, a3 = 0.f;
#pragma unroll
                for (int k = 0; k < 8; ++k) {
                    a0 = fmaf(xw0[0 + k], kv[k], a0);
                    a1 = fmaf(xw0[3 + k], kv[k], a1);
                    a2 = fmaf(xw0[6 + k], kv[k], a2);
                    a3 = fmaf(xw0[9 + k], kv[k], a3);
                }
                f32x4 o = {a0, a1, a2, a3};
                *reinterpret_cast<f32x4*>(orow + 4 * ch0) = o;
            }
            if (p1) {
                float a0 = 0.f, a1 = 0.f, a2 = 0.f, a3 = 0.f;
#pragma unroll
                for (int k = 0; k < 8; ++k) {
                    a0 = fmaf(xw1[0 + k], kv[k], a0);
                    a1 = fmaf(xw1[3 + k], kv[k], a1);
                    a2 = fmaf(xw1[6 + k], kv[k], a2);
                    a3 = fmaf(xw1[9 + k], kv[k], a3);
                }
                f32x4 o = {a0, a1, a2, a3};
                *reinterpret_cast<f32x4*>(orow + 4 * ch1) = o;
            }
        }
        if (c == 0 && r == 7) {                  // row 511 (kern 73, ch 0)
            const float* kr = kern + 73 * Kn;
            float kv[8];
#pragma unroll
            for (int k = 0; k < 8; ++k) kv[k] = kr[k];
            float* orow = ob + (size_t)511 * Wn;
            {
                float a0 = 0.f, a1 = 0.f, a2 = 0.f, a3 = 0.f;
#pragma unroll
                for (int k = 0; k < 8; ++k) {
                    a0 = fmaf(xw0[0 + k], kv[k], a0);
                    a1 = fmaf(xw0[3 + k], kv[k], a1);
                    a2 = fmaf(xw0[6 + k], kv[k], a2);
                    a3 = fmaf(xw0[9 + k], kv[k], a3);
                }
                f32x4 o = {a0, a1, a2, a3};
                *reinterpret_cast<f32x4*>(orow + 4 * ch0) = o;
            }
            if (p1) {
                float a0 = 0.f, a1 = 0.f, a2 = 0.f, a3 = 0.f;
#pragma unroll
                for (int k = 0; k < 8; ++k) {
                    a0 = fmaf(xw1[0 + k], kv[k], a0);
                    a1 = fmaf(xw1[3 + k], kv[k], a1);
                    a2 = fmaf(xw1[6 + k], kv[k], a2);
                    a3 = fmaf(xw1[9 + k], kv[k], a3);
                }
                f32x4 o = {a0, a1, a2, a3};
                *reinterpret_cast<f32x4*>(orow + 4 * ch1) = o;
            }
        }
    }
}

extern "C" void kernel_launch(void* const* d_in, const int* in_sizes, int n_in,
                              void* d_out, int out_size, void* d_ws, size_t ws_size,
                              hipStream_t stream) {
    const float* x    = (const float*)d_in[0];
    const float* kern = (const float*)d_in[1];
    float* out        = (float*)d_out;

    conv_v10<<<dim3(8, Bn), 512, 0, stream>>>(x, kern, out);
}